// Round 3
// baseline (321466.528 us; speedup 1.0000x reference)
//
#include <hip/hip_runtime.h>
#include <math.h>

#define T_STEPS 4096
#define EMB 1024
#define HID 2048
#define CAT 1040
#define TAG 16
#define NBLK 256
#define NTHR 1024

// ---- workspace layout (bytes) ----
#define WS_BAR   0                            // 2 x u32 barrier state (pad 256)
#define WS_HBUF  256                          // 2 * 2048 f32 = 16384
#define WS_TP    (WS_HBUF + 2 * HID * 4)      // 16 * 256 f32 = 16384
#define WS_VT    (WS_TP + TAG * NBLK * 4)     // 16 * 1024 f32 = 65536
#define WS_U     (WS_VT + TAG * EMB * 4)      // 4096 * 1024 f32
#define WS_ZERO  (WS_TP + TAG * NBLK * 4)     // zero bar + hbuf + tp

// output offsets (floats)
#define OUT_LOGP 0
#define OUT_PROB (T_STEPS * TAG)
#define OUT_PRED (2 * T_STEPS * TAG)

__device__ __forceinline__ float sigf(float x) { return 1.0f / (1.0f + expf(-x)); }

// device-scope (agent) sense/generation grid barrier
__device__ __forceinline__ void gbar(unsigned* cnt, unsigned* gen, unsigned nblk) {
  __syncthreads();
  if (threadIdx.x == 0) {
    __threadfence();  // release prior global writes (agent scope)
    unsigned g = __hip_atomic_load(gen, __ATOMIC_RELAXED, __HIP_MEMORY_SCOPE_AGENT);
    unsigned a = __hip_atomic_fetch_add(cnt, 1u, __ATOMIC_ACQ_REL, __HIP_MEMORY_SCOPE_AGENT);
    if (a == nblk - 1u) {
      __hip_atomic_store(cnt, 0u, __ATOMIC_RELAXED, __HIP_MEMORY_SCOPE_AGENT);
      __hip_atomic_fetch_add(gen, 1u, __ATOMIC_RELEASE, __HIP_MEMORY_SCOPE_AGENT);
    } else {
      while (__hip_atomic_load(gen, __ATOMIC_ACQUIRE, __HIP_MEMORY_SCOPE_AGENT) == g)
        __builtin_amdgcn_s_sleep(4);
    }
    __threadfence();  // acquire: invalidate stale cached lines for this CU
  }
  __syncthreads();
}

// ---- VT[p][i] = W_embed[i][1024+p]  (compact one-hot columns) ----
__global__ __launch_bounds__(256) void rnnss_vt_kernel(const float* __restrict__ We,
                                                       float* __restrict__ VT) {
  int n = blockIdx.x * 256 + threadIdx.x;      // 0..16383
  int p = n >> 10, i = n & 1023;
  VT[n] = We[(size_t)i * CAT + EMB + p];
}

// ---- U[t][i] = sum_k seq[t][k] * W_embed[i][k] + b_embed[i] ----
// C = A(4096x1024, rm) . B^T(1024 rows of W_embed, ld=1040), tiled 64x64x32
__global__ __launch_bounds__(256) void rnnss_uprep(const float* __restrict__ X,
                                                   const float* __restrict__ W,
                                                   const float* __restrict__ be,
                                                   float* __restrict__ U) {
  __shared__ __align__(16) float As[32][68];   // [k][m], pad->16B aligned rows
  __shared__ __align__(16) float Bs[32][68];   // [k][n]
  const int bm = blockIdx.x * 64;
  const int bn = blockIdx.y * 64;
  const int tid = threadIdx.x;
  const int tx = tid & 15, ty = tid >> 4;
  const int lr = tid >> 5, lc = tid & 31;      // loader: row 0..7, col 0..31
  float acc[4][4] = {};
  for (int k0 = 0; k0 < EMB; k0 += 32) {
#pragma unroll
    for (int p = 0; p < 8; ++p) {
      As[lc][lr + 8 * p] = X[(size_t)(bm + lr + 8 * p) * EMB + k0 + lc];
      Bs[lc][lr + 8 * p] = W[(size_t)(bn + lr + 8 * p) * CAT + k0 + lc];
    }
    __syncthreads();
#pragma unroll 8
    for (int k = 0; k < 32; ++k) {
      const float4 a = *(const float4*)&As[k][ty * 4];
      const float4 v = *(const float4*)&Bs[k][tx * 4];
      float am[4] = {a.x, a.y, a.z, a.w};
      float bv[4] = {v.x, v.y, v.z, v.w};
#pragma unroll
      for (int m = 0; m < 4; ++m)
#pragma unroll
        for (int n = 0; n < 4; ++n) acc[m][n] = fmaf(am[m], bv[n], acc[m][n]);
    }
    __syncthreads();
  }
#pragma unroll
  for (int m = 0; m < 4; ++m)
#pragma unroll
    for (int n = 0; n < 4; ++n)
      U[(size_t)(bm + ty * 4 + m) * EMB + bn + tx * 4 + n] =
          acc[m][n] + be[bn + tx * 4 + n];
}

// ---- persistent LSTM labeler: 256 blocks x 1024 threads, 2 grid barriers/step
__global__ __launch_bounds__(NTHR) void rnnss_persist(
    const float* __restrict__ Wih, const float* __restrict__ Whh,
    const float* __restrict__ bih, const float* __restrict__ bhh,
    const float* __restrict__ Witm, const float* __restrict__ bitm,
    const float* __restrict__ Wtag, const float* __restrict__ btag,
    const float* __restrict__ U, const float* __restrict__ VT,
    float* __restrict__ hbuf,   // [2][2048], zeroed by memset
    float* __restrict__ tpg,    // [16][256]
    unsigned* __restrict__ bar, // cnt, gen (zeroed)
    float* __restrict__ out) {
  __shared__ __align__(16) float se[EMB];
  __shared__ __align__(16) float sh[HID];
  __shared__ float sg[32];     // gate preacts for this block's 8 units
  __shared__ float wpart[16];  // per-wave partials (phase B)
  __shared__ float siv[4];     // interm values for this block's 4 rows
  __shared__ float stv[TAG];   // reduced tag scores
  __shared__ float sc[8];      // persistent cell state (block-owned units)

  const int tid = threadIdx.x;
  const int b = blockIdx.x;
  const int u0 = b * 8;                 // hidden units [u0, u0+8)
  if (tid < 8) sc[tid] = 0.0f;

  // phase A row task: 32 gate rows x 32 lanes
  const int rt = tid >> 5;              // 0..31 : g*8 + j
  const int q = tid & 31;
  const int gsec = rt >> 3, j = rt & 7;
  const int grow = gsec * HID + u0 + j;
  const float bsum = bih[grow] + bhh[grow];
  const float4* __restrict__ wi = (const float4*)(Wih + (size_t)grow * EMB);
  const float4* __restrict__ wh = (const float4*)(Whh + (size_t)grow * HID);

  // phase B row task: 4 interm rows x 256 lanes
  const int brow = tid >> 8, bq = tid & 255;
  const float4* __restrict__ wm = (const float4*)(Witm + (size_t)(b * 4 + brow) * HID);
  float bitv = 0.0f;
  if (tid < 4) bitv = bitm[b * 4 + tid];
  float wt0 = 0, wt1 = 0, wt2 = 0, wt3 = 0;
  if (tid < TAG) {
    wt0 = Wtag[(size_t)tid * 1024 + b * 4 + 0];
    wt1 = Wtag[(size_t)tid * 1024 + b * 4 + 1];
    wt2 = Wtag[(size_t)tid * 1024 + b * 4 + 2];
    wt3 = Wtag[(size_t)tid * 1024 + b * 4 + 3];
  }
  float btw = 0.0f;
  if ((tid & 63) == 0) btw = btag[tid >> 6];

  const float4* sef = (const float4*)se;
  const float4* shf = (const float4*)sh;

  int pred = 0;  // __START__

  for (int t = 0; t < T_STEPS; ++t) {
    const float* __restrict__ hb = hbuf + (size_t)(t & 1) * HID;        // h_{t-1}
    float* __restrict__ hn = hbuf + (size_t)((t + 1) & 1) * HID;        // h_t

    // ---- phase A: stage e, h; gates; LSTM pointwise ----
    {
      float ev = U[(size_t)t * EMB + tid] + VT[(size_t)pred * EMB + tid];
      se[tid] = ev > 0.0f ? ev : 0.0f;
      sh[tid] = hb[tid];
      sh[tid + 1024] = hb[tid + 1024];
    }
    __syncthreads();
    float acc = 0.0f;
#pragma unroll
    for (int it = 0; it < 8; ++it) {   // e part: 1024
      float4 w = wi[q + 32 * it], x = sef[q + 32 * it];
      acc += w.x * x.x + w.y * x.y + w.z * x.z + w.w * x.w;
    }
#pragma unroll 8
    for (int it = 0; it < 16; ++it) {  // h part: 2048
      float4 w = wh[q + 32 * it], x = shf[q + 32 * it];
      acc += w.x * x.x + w.y * x.y + w.z * x.z + w.w * x.w;
    }
#pragma unroll
    for (int d = 16; d > 0; d >>= 1) acc += __shfl_down(acc, d, 32);
    if (q == 0) sg[rt] = acc + bsum;
    __syncthreads();
    if (tid < 8) {
      float iv = sigf(sg[tid]);
      float fv = sigf(sg[8 + tid]);
      float gv = tanhf(sg[16 + tid]);
      float ov = sigf(sg[24 + tid]);
      float c = fv * sc[tid] + iv * gv;
      sc[tid] = c;
      hn[u0 + tid] = ov * tanhf(c);
    }
    gbar(bar, bar + 1, NBLK);

    // ---- phase B: interm rows + tag partials ----
    sh[tid] = hn[tid];
    sh[tid + 1024] = hn[tid + 1024];
    __syncthreads();
    {
      float a2 = 0.0f;
#pragma unroll
      for (int it = 0; it < 2; ++it) {  // 2048
        float4 w = wm[bq + 256 * it], x = shf[bq + 256 * it];
        a2 += w.x * x.x + w.y * x.y + w.z * x.z + w.w * x.w;
      }
#pragma unroll
      for (int d = 32; d > 0; d >>= 1) a2 += __shfl_down(a2, d, 64);
      if ((tid & 63) == 0) wpart[tid >> 6] = a2;
      __syncthreads();
      if (tid < 4) {
        float v = wpart[tid * 4] + wpart[tid * 4 + 1] + wpart[tid * 4 + 2] +
                  wpart[tid * 4 + 3] + bitv;
        siv[tid] = v > 0.0f ? v : 0.0f;
      }
      __syncthreads();
      if (tid < TAG) {
        float tpv = wt0 * siv[0] + wt1 * siv[1] + wt2 * siv[2] + wt3 * siv[3];
        tpg[tid * NBLK + b] = tpv;
      }
    }
    gbar(bar, bar + 1, NBLK);

    // ---- phase C: reduce tags, softmax, argmax (redundant in every block) ----
    {
      const int w = tid >> 6, l = tid & 63;  // 16 waves == 16 tags
      float v = tpg[w * NBLK + l] + tpg[w * NBLK + 64 + l] +
                tpg[w * NBLK + 128 + l] + tpg[w * NBLK + 192 + l];
#pragma unroll
      for (int d = 32; d > 0; d >>= 1) v += __shfl_down(v, d, 64);
      if (l == 0) stv[w] = v + btw;
      __syncthreads();
      float m = stv[0];
#pragma unroll
      for (int k = 1; k < TAG; ++k) m = fmaxf(m, stv[k]);
      float s = 0.0f;
#pragma unroll
      for (int k = 0; k < TAG; ++k) s += expf(stv[k] - m);
      float ls = logf(s);
      int am = 0;
      float bv = stv[0];
#pragma unroll
      for (int k = 1; k < TAG; ++k) {
        if (stv[k] > bv) { bv = stv[k]; am = k; }
      }
      pred = am;
      if (b == 0) {
        if (tid < TAG) {
          float lp = stv[tid] - m - ls;
          out[OUT_LOGP + t * TAG + tid] = lp;
          out[OUT_PROB + t * TAG + tid] = expf(lp);
        } else if (tid == TAG) {
          out[OUT_PRED + t] = (float)am;
        }
      }
      __syncthreads();
    }
  }
}

extern "C" void kernel_launch(void* const* d_in, const int* in_sizes, int n_in,
                              void* d_out, int out_size, void* d_ws, size_t ws_size,
                              hipStream_t stream) {
  const float* seq = (const float*)d_in[0];
  const float* W_embed = (const float*)d_in[1];
  const float* b_embed = (const float*)d_in[2];
  const float* W_ih = (const float*)d_in[3];
  const float* W_hh = (const float*)d_in[4];
  const float* b_ih = (const float*)d_in[5];
  const float* b_hh = (const float*)d_in[6];
  const float* W_interm = (const float*)d_in[7];
  const float* b_interm = (const float*)d_in[8];
  const float* W_tag = (const float*)d_in[9];
  const float* b_tag = (const float*)d_in[10];
  (void)in_sizes; (void)n_in; (void)out_size; (void)ws_size;

  char* ws = (char*)d_ws;
  unsigned* bar = (unsigned*)(ws + WS_BAR);
  float* hbuf = (float*)(ws + WS_HBUF);
  float* tpg = (float*)(ws + WS_TP);
  float* VT = (float*)(ws + WS_VT);
  float* U = (float*)(ws + WS_U);
  float* out = (float*)d_out;

  // reset barrier state, h buffers, tag partials every call (ws is poisoned)
  hipMemsetAsync(ws, 0, WS_ZERO, stream);

  hipLaunchKernelGGL(rnnss_vt_kernel, dim3((TAG * EMB) / 256), dim3(256), 0, stream,
                     W_embed, VT);
  hipLaunchKernelGGL(rnnss_uprep, dim3(T_STEPS / 64, EMB / 64), dim3(256), 0, stream,
                     seq, W_embed, b_embed, U);

  void* args[] = {
      (void*)&W_ih,    (void*)&W_hh,  (void*)&b_ih,  (void*)&b_hh,
      (void*)&W_interm,(void*)&b_interm, (void*)&W_tag, (void*)&b_tag,
      (void*)&U,       (void*)&VT,    (void*)&hbuf,  (void*)&tpg,
      (void*)&bar,     (void*)&out};
  hipLaunchCooperativeKernel((const void*)rnnss_persist, dim3(NBLK), dim3(NTHR),
                             args, 0, stream);
}

// Round 4
// 157403.967 us; speedup vs baseline: 2.0423x; 2.0423x over previous
//
#include <hip/hip_runtime.h>
#include <math.h>

#define T_STEPS 4096
#define EMB 1024
#define HID 2048
#define CAT 1040
#define TAG 16
#define NBLK 256
#define NTHR 1024
#define FLAG_STRIDE 32   // u32s per arrival-flag slot = 128B (own cacheline)

// ---- workspace layout (bytes) ----
#define WS_ARR  0                               // 256 * 128B = 32768
#define WS_HBUF (NBLK * FLAG_STRIDE * 4)        // 32768: 2 * 2048 f32
#define WS_TP   (WS_HBUF + 2 * HID * 4)         // 49152: 16 * 256 f32
#define WS_VT   (WS_TP + TAG * NBLK * 4)        // 65536: 16 * 1024 f32
#define WS_U    (WS_VT + TAG * EMB * 4)         // 131072: 4096 * 1024 f32
#define WS_ZERO WS_VT                           // zero arr + hbuf + tp

// output offsets (floats)
#define OUT_LOGP 0
#define OUT_PROB (T_STEPS * TAG)
#define OUT_PRED (2 * T_STEPS * TAG)

__device__ __forceinline__ float sigf(float x) { return 1.0f / (1.0f + expf(-x)); }

// Symmetric all-poll grid barrier.
// Arrival: per-block release store to its OWN 128B flag slot (no RMW, no
// same-address contention). Wait: threads 0..255 of EVERY block poll all 256
// flags with relaxed agent-scope loads (atomics bypass L1 and are serviced at
// the coherent point, so no stale-L2 deadlock). One __threadfence() afterward
// invalidates stale cached lines so subsequent PLAIN loads of h/tpg are fresh
// (same fence pattern that passed correctness in R2 across 8192 barriers).
__device__ __forceinline__ void gbar(unsigned* __restrict__ arr, unsigned epoch) {
  const int tid = threadIdx.x;
  __syncthreads();
  if (tid == 0) {
    __threadfence();  // make this block's prior global writes visible (agent)
    __hip_atomic_store(arr + (size_t)blockIdx.x * FLAG_STRIDE, epoch,
                       __ATOMIC_RELEASE, __HIP_MEMORY_SCOPE_AGENT);
  }
  if (tid < NBLK) {
    const unsigned* f = arr + (size_t)tid * FLAG_STRIDE;
    while (__hip_atomic_load(f, __ATOMIC_RELAXED, __HIP_MEMORY_SCOPE_AGENT) < epoch)
      __builtin_amdgcn_s_sleep(1);
  }
  __syncthreads();
  if (tid == 0) __threadfence();  // acquire side: invalidate stale cache lines
  __syncthreads();
}

// ---- VT[p][i] = W_embed[i][1024+p]  (compact one-hot columns) ----
__global__ __launch_bounds__(256) void rnnss_vt_kernel(const float* __restrict__ We,
                                                       float* __restrict__ VT) {
  int n = blockIdx.x * 256 + threadIdx.x;      // 0..16383
  int p = n >> 10, i = n & 1023;
  VT[n] = We[(size_t)i * CAT + EMB + p];
}

// ---- U[t][i] = sum_k seq[t][k] * W_embed[i][k] + b_embed[i] ----
__global__ __launch_bounds__(256) void rnnss_uprep(const float* __restrict__ X,
                                                   const float* __restrict__ W,
                                                   const float* __restrict__ be,
                                                   float* __restrict__ U) {
  __shared__ __align__(16) float As[32][68];
  __shared__ __align__(16) float Bs[32][68];
  const int bm = blockIdx.x * 64;
  const int bn = blockIdx.y * 64;
  const int tid = threadIdx.x;
  const int tx = tid & 15, ty = tid >> 4;
  const int lr = tid >> 5, lc = tid & 31;
  float acc[4][4] = {};
  for (int k0 = 0; k0 < EMB; k0 += 32) {
#pragma unroll
    for (int p = 0; p < 8; ++p) {
      As[lc][lr + 8 * p] = X[(size_t)(bm + lr + 8 * p) * EMB + k0 + lc];
      Bs[lc][lr + 8 * p] = W[(size_t)(bn + lr + 8 * p) * CAT + k0 + lc];
    }
    __syncthreads();
#pragma unroll 8
    for (int k = 0; k < 32; ++k) {
      const float4 a = *(const float4*)&As[k][ty * 4];
      const float4 v = *(const float4*)&Bs[k][tx * 4];
      float am[4] = {a.x, a.y, a.z, a.w};
      float bv[4] = {v.x, v.y, v.z, v.w};
#pragma unroll
      for (int m = 0; m < 4; ++m)
#pragma unroll
        for (int n = 0; n < 4; ++n) acc[m][n] = fmaf(am[m], bv[n], acc[m][n]);
    }
    __syncthreads();
  }
#pragma unroll
  for (int m = 0; m < 4; ++m)
#pragma unroll
    for (int n = 0; n < 4; ++n)
      U[(size_t)(bm + ty * 4 + m) * EMB + bn + tx * 4 + n] =
          acc[m][n] + be[bn + tx * 4 + n];
}

// ---- persistent LSTM labeler: 256 blocks x 1024 threads ----
// Weights held register-resident: 26 float4/thread (W_ih 8, W_hh 16, W_interm 2)
// = 104 VGPR of weights; loaded once in prologue, zero weight streaming per step.
__global__ __launch_bounds__(NTHR, 4) void rnnss_persist(
    const float* __restrict__ Wih, const float* __restrict__ Whh,
    const float* __restrict__ bih, const float* __restrict__ bhh,
    const float* __restrict__ Witm, const float* __restrict__ bitm,
    const float* __restrict__ Wtag, const float* __restrict__ btag,
    const float* __restrict__ U, const float* __restrict__ VT,
    float* __restrict__ hbuf,   // [2][2048], zeroed by memset
    float* __restrict__ tpg,    // [16][256]
    unsigned* __restrict__ arr, // arrival flags (zeroed)
    float* __restrict__ out) {
  __shared__ __align__(16) float se[EMB];
  __shared__ __align__(16) float sh[HID];
  __shared__ float sg[32];     // gate preacts for this block's 8 units
  __shared__ float wpart[16];  // per-wave partials (phase B)
  __shared__ float siv[4];     // interm values for this block's 4 rows
  __shared__ float stv[TAG];   // reduced tag scores
  __shared__ float sc[8];      // persistent cell state (block-owned units)

  const int tid = threadIdx.x;
  const int b = blockIdx.x;
  const int u0 = b * 8;                 // hidden units [u0, u0+8)
  if (tid < 8) sc[tid] = 0.0f;

  // phase A row task: 32 gate rows x 32 lanes
  const int rt = tid >> 5;              // 0..31 : g*8 + j
  const int q = tid & 31;
  const int gsec = rt >> 3, j = rt & 7;
  const int grow = gsec * HID + u0 + j;
  const float bsum = bih[grow] + bhh[grow];
  const float4* __restrict__ wi = (const float4*)(Wih + (size_t)grow * EMB);
  const float4* __restrict__ wh = (const float4*)(Whh + (size_t)grow * HID);

  // phase B row task: 4 interm rows x 256 lanes
  const int brow = tid >> 8, bq = tid & 255;
  const float4* __restrict__ wm = (const float4*)(Witm + (size_t)(b * 4 + brow) * HID);
  float bitv = 0.0f;
  if (tid < 4) bitv = bitm[b * 4 + tid];
  float wt0 = 0, wt1 = 0, wt2 = 0, wt3 = 0;
  if (tid < TAG) {
    wt0 = Wtag[(size_t)tid * 1024 + b * 4 + 0];
    wt1 = Wtag[(size_t)tid * 1024 + b * 4 + 1];
    wt2 = Wtag[(size_t)tid * 1024 + b * 4 + 2];
    wt3 = Wtag[(size_t)tid * 1024 + b * 4 + 3];
  }
  float btw = 0.0f;
  if ((tid & 63) == 0) btw = btag[tid >> 6];

  // ---- prologue: pull this thread's weight slices into registers ----
  float4 rwi[8], rwh[16], rwm[2];
#pragma unroll
  for (int it = 0; it < 8; ++it) rwi[it] = wi[q + 32 * it];
#pragma unroll
  for (int it = 0; it < 16; ++it) rwh[it] = wh[q + 32 * it];
  rwm[0] = wm[bq];
  rwm[1] = wm[bq + 256];

  const float4* sef = (const float4*)se;
  const float4* shf = (const float4*)sh;

  int pred = 0;  // __START__

  for (int t = 0; t < T_STEPS; ++t) {
    const float* __restrict__ hb = hbuf + (size_t)(t & 1) * HID;        // h_{t-1}
    float* __restrict__ hn = hbuf + (size_t)((t + 1) & 1) * HID;        // h_t
    const unsigned ep = 2u * (unsigned)t + 1u;

    // ---- phase A: stage e, h; gates from registers; LSTM pointwise ----
    {
      float ev = U[(size_t)t * EMB + tid] + VT[(size_t)pred * EMB + tid];
      se[tid] = ev > 0.0f ? ev : 0.0f;
      sh[tid] = hb[tid];
      sh[tid + 1024] = hb[tid + 1024];
    }
    __syncthreads();
    float acc0 = 0.0f, acc1 = 0.0f;
#pragma unroll
    for (int it = 0; it < 8; ++it) {   // e part: 1024
      float4 w = rwi[it], x = sef[q + 32 * it];
      acc0 += w.x * x.x + w.y * x.y + w.z * x.z + w.w * x.w;
    }
#pragma unroll
    for (int it = 0; it < 16; ++it) {  // h part: 2048
      float4 w = rwh[it], x = shf[q + 32 * it];
      acc1 += w.x * x.x + w.y * x.y + w.z * x.z + w.w * x.w;
    }
    float acc = acc0 + acc1;
#pragma unroll
    for (int d = 16; d > 0; d >>= 1) acc += __shfl_down(acc, d, 32);
    if (q == 0) sg[rt] = acc + bsum;
    __syncthreads();
    if (tid < 8) {
      float iv = sigf(sg[tid]);
      float fv = sigf(sg[8 + tid]);
      float gv = tanhf(sg[16 + tid]);
      float ov = sigf(sg[24 + tid]);
      float c = fv * sc[tid] + iv * gv;
      sc[tid] = c;
      hn[u0 + tid] = ov * tanhf(c);
    }
    gbar(arr, ep);

    // ---- phase B: interm rows + tag partials (weights in registers) ----
    sh[tid] = hn[tid];
    sh[tid + 1024] = hn[tid + 1024];
    __syncthreads();
    {
      float a2 = 0.0f;
      {
        float4 w = rwm[0], x = shf[bq];
        a2 += w.x * x.x + w.y * x.y + w.z * x.z + w.w * x.w;
        w = rwm[1]; x = shf[bq + 256];
        a2 += w.x * x.x + w.y * x.y + w.z * x.z + w.w * x.w;
      }
#pragma unroll
      for (int d = 32; d > 0; d >>= 1) a2 += __shfl_down(a2, d, 64);
      if ((tid & 63) == 0) wpart[tid >> 6] = a2;
      __syncthreads();
      if (tid < 4) {
        float v = wpart[tid * 4] + wpart[tid * 4 + 1] + wpart[tid * 4 + 2] +
                  wpart[tid * 4 + 3] + bitv;
        siv[tid] = v > 0.0f ? v : 0.0f;
      }
      __syncthreads();
      if (tid < TAG) {
        float tpv = wt0 * siv[0] + wt1 * siv[1] + wt2 * siv[2] + wt3 * siv[3];
        tpg[tid * NBLK + b] = tpv;
      }
    }
    gbar(arr, ep + 1u);

    // ---- phase C: reduce tags, softmax, argmax (redundant in every block) ----
    {
      const int w = tid >> 6, l = tid & 63;  // 16 waves == 16 tags
      float v = tpg[w * NBLK + l] + tpg[w * NBLK + 64 + l] +
                tpg[w * NBLK + 128 + l] + tpg[w * NBLK + 192 + l];
#pragma unroll
      for (int d = 32; d > 0; d >>= 1) v += __shfl_down(v, d, 64);
      if (l == 0) stv[w] = v + btw;
      __syncthreads();
      float m = stv[0];
#pragma unroll
      for (int k = 1; k < TAG; ++k) m = fmaxf(m, stv[k]);
      float s = 0.0f;
#pragma unroll
      for (int k = 0; k < TAG; ++k) s += expf(stv[k] - m);
      float ls = logf(s);
      int am = 0;
      float bv = stv[0];
#pragma unroll
      for (int k = 1; k < TAG; ++k) {
        if (stv[k] > bv) { bv = stv[k]; am = k; }
      }
      pred = am;
      if (b == 0) {
        if (tid < TAG) {
          float lp = stv[tid] - m - ls;
          out[OUT_LOGP + t * TAG + tid] = lp;
          out[OUT_PROB + t * TAG + tid] = expf(lp);
        } else if (tid == TAG) {
          out[OUT_PRED + t] = (float)am;
        }
      }
      __syncthreads();
    }
  }
}

extern "C" void kernel_launch(void* const* d_in, const int* in_sizes, int n_in,
                              void* d_out, int out_size, void* d_ws, size_t ws_size,
                              hipStream_t stream) {
  const float* seq = (const float*)d_in[0];
  const float* W_embed = (const float*)d_in[1];
  const float* b_embed = (const float*)d_in[2];
  const float* W_ih = (const float*)d_in[3];
  const float* W_hh = (const float*)d_in[4];
  const float* b_ih = (const float*)d_in[5];
  const float* b_hh = (const float*)d_in[6];
  const float* W_interm = (const float*)d_in[7];
  const float* b_interm = (const float*)d_in[8];
  const float* W_tag = (const float*)d_in[9];
  const float* b_tag = (const float*)d_in[10];
  (void)in_sizes; (void)n_in; (void)out_size; (void)ws_size;

  char* ws = (char*)d_ws;
  unsigned* arr = (unsigned*)(ws + WS_ARR);
  float* hbuf = (float*)(ws + WS_HBUF);
  float* tpg = (float*)(ws + WS_TP);
  float* VT = (float*)(ws + WS_VT);
  float* U = (float*)(ws + WS_U);
  float* out = (float*)d_out;

  // reset arrival flags, h buffers, tag partials every call (ws is poisoned)
  hipMemsetAsync(ws, 0, WS_ZERO, stream);

  hipLaunchKernelGGL(rnnss_vt_kernel, dim3((TAG * EMB) / 256), dim3(256), 0, stream,
                     W_embed, VT);
  hipLaunchKernelGGL(rnnss_uprep, dim3(T_STEPS / 64, EMB / 64), dim3(256), 0, stream,
                     seq, W_embed, b_embed, U);

  void* args[] = {
      (void*)&W_ih,    (void*)&W_hh,  (void*)&b_ih,  (void*)&b_hh,
      (void*)&W_interm,(void*)&b_interm, (void*)&W_tag, (void*)&b_tag,
      (void*)&U,       (void*)&VT,    (void*)&hbuf,  (void*)&tpg,
      (void*)&arr,     (void*)&out};
  hipLaunchCooperativeKernel((const void*)rnnss_persist, dim3(NBLK), dim3(NTHR),
                             args, 0, stream);
}

// Round 5
// 37613.385 us; speedup vs baseline: 8.5466x; 4.1848x over previous
//
#include <hip/hip_runtime.h>
#include <math.h>

#define T_STEPS 4096
#define EMB 1024
#define HID 2048
#define CAT 1040
#define TAG 16
#define NBLK 256
#define NTHR 1024
#define FLAG_STRIDE 32   // u32s per arrival-flag slot = 128B (own cacheline)

// ---- workspace layout (bytes) ----
#define WS_ARR  0                               // 256 * 128B = 32768
#define WS_HBUF (NBLK * FLAG_STRIDE * 4)        // 32768: 2 * 2048 f32
#define WS_TP   (WS_HBUF + 2 * HID * 4)         // 49152: 16 * 256 f32
#define WS_VT   (WS_TP + TAG * NBLK * 4)        // 65536: 16 * 1024 f32
#define WS_U    (WS_VT + TAG * EMB * 4)         // 131072: 4096 * 1024 f32
#define WS_ZERO WS_VT                           // zero arr + hbuf + tp

// output offsets (floats)
#define OUT_LOGP 0
#define OUT_PROB (T_STEPS * TAG)
#define OUT_PRED (2 * T_STEPS * TAG)

__device__ __forceinline__ float sigf(float x) { return 1.0f / (1.0f + expf(-x)); }

__device__ __forceinline__ float aload(const float* p) {
  return __hip_atomic_load(p, __ATOMIC_RELAXED, __HIP_MEMORY_SCOPE_AGENT);
}
__device__ __forceinline__ void astore(float* p, float v) {
  __hip_atomic_store(p, v, __ATOMIC_RELAXED, __HIP_MEMORY_SCOPE_AGENT);
}

// Fence-FREE grid barrier. No release/acquire ops anywhere -> compiler never
// emits buffer_wbl2/buffer_inv -> per-XCD L2 keeps weights/U/VT cached across
// all 8192 barriers. Correctness contract:
//  - ALL cross-block data (hn, tpg) is written with relaxed AGENT-scope atomic
//    stores (sc-flagged: write through to the coherent point, bypass L2) and
//    read with relaxed AGENT-scope atomic loads (bypass stale caches).
//  - All such stores are issued by WAVE 0 of each block (tid<16), the same
//    wave that stores the flag; the raw `s_waitcnt vmcnt(0)` below therefore
//    covers them by wave program order before the flag becomes visible.
//  - Readers observe the flag via a dependent poll loop (no load speculation
//    past an unresolved branch), then issue data loads that are serviced at
//    the coherent point; compiler reordering is blocked by the "memory" asm.
__device__ __forceinline__ void gbar_ff(unsigned* __restrict__ arr, unsigned epoch) {
  const int tid = threadIdx.x;
  __syncthreads();
  if (tid == 0) {
    asm volatile("s_waitcnt vmcnt(0)" ::: "memory");
    __hip_atomic_store(arr + (size_t)blockIdx.x * FLAG_STRIDE, epoch,
                       __ATOMIC_RELAXED, __HIP_MEMORY_SCOPE_AGENT);
  }
  if (tid < NBLK) {
    const unsigned* f = arr + (size_t)tid * FLAG_STRIDE;
    while (__hip_atomic_load(f, __ATOMIC_RELAXED, __HIP_MEMORY_SCOPE_AGENT) < epoch)
      __builtin_amdgcn_s_sleep(1);
  }
  asm volatile("" ::: "memory");  // compiler-only: keep data loads after poll
  __syncthreads();
}

// ---- VT[p][i] = W_embed[i][1024+p]  (compact one-hot columns) ----
__global__ __launch_bounds__(256) void rnnss_vt_kernel(const float* __restrict__ We,
                                                       float* __restrict__ VT) {
  int n = blockIdx.x * 256 + threadIdx.x;      // 0..16383
  int p = n >> 10, i = n & 1023;
  VT[n] = We[(size_t)i * CAT + EMB + p];
}

// ---- U[t][i] = sum_k seq[t][k] * W_embed[i][k] + b_embed[i] ----
__global__ __launch_bounds__(256) void rnnss_uprep(const float* __restrict__ X,
                                                   const float* __restrict__ W,
                                                   const float* __restrict__ be,
                                                   float* __restrict__ U) {
  __shared__ __align__(16) float As[32][68];
  __shared__ __align__(16) float Bs[32][68];
  const int bm = blockIdx.x * 64;
  const int bn = blockIdx.y * 64;
  const int tid = threadIdx.x;
  const int tx = tid & 15, ty = tid >> 4;
  const int lr = tid >> 5, lc = tid & 31;
  float acc[4][4] = {};
  for (int k0 = 0; k0 < EMB; k0 += 32) {
#pragma unroll
    for (int p = 0; p < 8; ++p) {
      As[lc][lr + 8 * p] = X[(size_t)(bm + lr + 8 * p) * EMB + k0 + lc];
      Bs[lc][lr + 8 * p] = W[(size_t)(bn + lr + 8 * p) * CAT + k0 + lc];
    }
    __syncthreads();
#pragma unroll 8
    for (int k = 0; k < 32; ++k) {
      const float4 a = *(const float4*)&As[k][ty * 4];
      const float4 v = *(const float4*)&Bs[k][tx * 4];
      float am[4] = {a.x, a.y, a.z, a.w};
      float bv[4] = {v.x, v.y, v.z, v.w};
#pragma unroll
      for (int m = 0; m < 4; ++m)
#pragma unroll
        for (int n = 0; n < 4; ++n) acc[m][n] = fmaf(am[m], bv[n], acc[m][n]);
    }
    __syncthreads();
  }
#pragma unroll
  for (int m = 0; m < 4; ++m)
#pragma unroll
    for (int n = 0; n < 4; ++n)
      U[(size_t)(bm + ty * 4 + m) * EMB + bn + tx * 4 + n] =
          acc[m][n] + be[bn + tx * 4 + n];
}

// ---- persistent LSTM labeler: 256 blocks x 1024 threads ----
// Fence-immune weight residency:
//   W_ih slice (32 rows x 1024 = 128 KB)  -> static LDS   (fences don't touch LDS)
//   W_hh slice (32 rows x 2048 = 256 KB)  -> 64 VGPR/thread, pinned via asm
//   W_interm slice (4 rows x 2048 = 32 KB)-> 8 VGPR/thread, pinned via asm
// Cross-block traffic (hn, tpg) via relaxed agent atomics; no fences at all.
__global__ __launch_bounds__(NTHR, 4) void rnnss_persist(
    const float* __restrict__ Wih, const float* __restrict__ Whh,
    const float* __restrict__ bih, const float* __restrict__ bhh,
    const float* __restrict__ Witm, const float* __restrict__ bitm,
    const float* __restrict__ Wtag, const float* __restrict__ btag,
    const float* __restrict__ U, const float* __restrict__ VT,
    float* __restrict__ hbuf,   // [2][2048], zeroed by memset
    float* __restrict__ tpg,    // [16][256]
    unsigned* __restrict__ arr, // arrival flags (zeroed)
    float* __restrict__ out) {
  __shared__ __align__(16) float sWi[32 * 1024];  // 128 KB: this block's W_ih rows
  __shared__ __align__(16) float se[EMB];
  __shared__ __align__(16) float sh[HID];
  __shared__ float sg[32];     // gate preacts for this block's 8 units
  __shared__ float wpart[16];  // per-wave partials (phase B)
  __shared__ float siv[4];     // interm values for this block's 4 rows
  __shared__ float stv[TAG];   // reduced tag scores
  __shared__ float sc[8];      // persistent cell state (block-owned units)

  const int tid = threadIdx.x;
  const int b = blockIdx.x;
  const int u0 = b * 8;                 // hidden units [u0, u0+8)
  if (tid < 8) sc[tid] = 0.0f;

  // phase A row task: 32 gate rows x 32 lanes
  const int rt = tid >> 5;              // 0..31 : gsec*8 + j
  const int q = tid & 31;
  const int gsec = rt >> 3, j = rt & 7;
  const int grow = gsec * HID + u0 + j;
  const float bsum = bih[grow] + bhh[grow];
  const float4* __restrict__ wh = (const float4*)(Whh + (size_t)grow * HID);

  // phase B row task: 4 interm rows x 256 lanes
  const int brow = tid >> 8, bq = tid & 255;
  const float4* __restrict__ wm = (const float4*)(Witm + (size_t)(b * 4 + brow) * HID);
  float bitv = 0.0f;
  if (tid < 4) bitv = bitm[b * 4 + tid];
  float wt0 = 0, wt1 = 0, wt2 = 0, wt3 = 0;
  if (tid < TAG) {
    wt0 = Wtag[(size_t)tid * 1024 + b * 4 + 0];
    wt1 = Wtag[(size_t)tid * 1024 + b * 4 + 1];
    wt2 = Wtag[(size_t)tid * 1024 + b * 4 + 2];
    wt3 = Wtag[(size_t)tid * 1024 + b * 4 + 3];
  }
  float btw = 0.0f;
  if ((tid & 63) == 0) btw = btag[tid >> 6];

  // ---- prologue: W_ih slice -> LDS (coalesced float4) ----
  {
    const float4* WiF = (const float4*)Wih;
    float4* sWiF = (float4*)sWi;
#pragma unroll
    for (int n = 0; n < 8; ++n) {
      int idx = tid + 1024 * n;          // 0..8191 float4s
      int r = idx >> 8, c = idx & 255;
      int gr = (r >> 3) * HID + u0 + (r & 7);
      sWiF[idx] = WiF[(size_t)gr * 256 + c];
    }
  }

  // ---- prologue: W_hh + W_interm slices -> registers, PINNED ----
  float4 rwh[16], rwm[2];
#pragma unroll
  for (int it = 0; it < 16; ++it) rwh[it] = wh[q + 32 * it];
  rwm[0] = wm[bq];
  rwm[1] = wm[bq + 256];
  // Opaque-ify every component so the compiler cannot rematerialize the loads
  // inside the t-loop (the R4 failure: VGPR_Count=64 proved it sank them).
#pragma unroll
  for (int it = 0; it < 16; ++it)
    asm volatile("" : "+v"(rwh[it].x), "+v"(rwh[it].y), "+v"(rwh[it].z), "+v"(rwh[it].w));
  asm volatile("" : "+v"(rwm[0].x), "+v"(rwm[0].y), "+v"(rwm[0].z), "+v"(rwm[0].w));
  asm volatile("" : "+v"(rwm[1].x), "+v"(rwm[1].y), "+v"(rwm[1].z), "+v"(rwm[1].w));

  const float4* sef = (const float4*)se;
  const float4* shf = (const float4*)sh;
  const float4* sWiF4 = (const float4*)sWi;

  int pred = 0;  // __START__
  __syncthreads();  // sWi / sc ready

  for (int t = 0; t < T_STEPS; ++t) {
    const float* __restrict__ hb = hbuf + (size_t)(t & 1) * HID;        // h_{t-1}
    float* __restrict__ hn = hbuf + (size_t)((t + 1) & 1) * HID;        // h_t
    const unsigned ep = 2u * (unsigned)t + 1u;

    // ---- phase A: stage e (plain, cacheable) and h (coherent atomic) ----
    {
      float ev = U[(size_t)t * EMB + tid] + VT[(size_t)pred * EMB + tid];
      se[tid] = ev > 0.0f ? ev : 0.0f;
      sh[tid] = aload(hb + tid);
      sh[tid + 1024] = aload(hb + tid + 1024);
    }
    __syncthreads();
    float acc0 = 0.0f, acc1 = 0.0f;
#pragma unroll
    for (int it = 0; it < 8; ++it) {   // e part: 1024 (weights from LDS)
      float4 w = sWiF4[rt * 256 + q + 32 * it], x = sef[q + 32 * it];
      acc0 += w.x * x.x + w.y * x.y + w.z * x.z + w.w * x.w;
    }
#pragma unroll
    for (int it = 0; it < 16; ++it) {  // h part: 2048 (weights from VGPRs)
      float4 w = rwh[it], x = shf[q + 32 * it];
      acc1 += w.x * x.x + w.y * x.y + w.z * x.z + w.w * x.w;
    }
    float acc = acc0 + acc1;
#pragma unroll
    for (int d = 16; d > 0; d >>= 1) acc += __shfl_down(acc, d, 32);
    if (q == 0) sg[rt] = acc + bsum;
    __syncthreads();
    if (tid < 8) {                      // wave 0: covered by gbar's vmcnt(0)
      float iv = sigf(sg[tid]);
      float fv = sigf(sg[8 + tid]);
      float gv = tanhf(sg[16 + tid]);
      float ov = sigf(sg[24 + tid]);
      float c = fv * sc[tid] + iv * gv;
      sc[tid] = c;
      astore(hn + u0 + tid, ov * tanhf(c));
    }
    gbar_ff(arr, ep);

    // ---- phase B: interm rows + tag partials (weights in registers) ----
    sh[tid] = aload(hn + tid);
    sh[tid + 1024] = aload(hn + tid + 1024);
    __syncthreads();
    {
      float a2 = 0.0f;
      {
        float4 w = rwm[0], x = shf[bq];
        a2 += w.x * x.x + w.y * x.y + w.z * x.z + w.w * x.w;
        w = rwm[1]; x = shf[bq + 256];
        a2 += w.x * x.x + w.y * x.y + w.z * x.z + w.w * x.w;
      }
#pragma unroll
      for (int d = 32; d > 0; d >>= 1) a2 += __shfl_down(a2, d, 64);
      if ((tid & 63) == 0) wpart[tid >> 6] = a2;
      __syncthreads();
      if (tid < 4) {
        float v = wpart[tid * 4] + wpart[tid * 4 + 1] + wpart[tid * 4 + 2] +
                  wpart[tid * 4 + 3] + bitv;
        siv[tid] = v > 0.0f ? v : 0.0f;
      }
      __syncthreads();
      if (tid < TAG) {                  // wave 0: covered by gbar's vmcnt(0)
        float tpv = wt0 * siv[0] + wt1 * siv[1] + wt2 * siv[2] + wt3 * siv[3];
        astore(tpg + tid * NBLK + b, tpv);
      }
    }
    gbar_ff(arr, ep + 1u);

    // ---- phase C: reduce tags, softmax, argmax (redundant in every block) ----
    {
      const int w = tid >> 6, l = tid & 63;  // 16 waves == 16 tags
      float v = aload(tpg + w * NBLK + l) + aload(tpg + w * NBLK + 64 + l) +
                aload(tpg + w * NBLK + 128 + l) + aload(tpg + w * NBLK + 192 + l);
#pragma unroll
      for (int d = 32; d > 0; d >>= 1) v += __shfl_down(v, d, 64);
      if (l == 0) stv[w] = v + btw;
      __syncthreads();
      float m = stv[0];
#pragma unroll
      for (int k = 1; k < TAG; ++k) m = fmaxf(m, stv[k]);
      float s = 0.0f;
#pragma unroll
      for (int k = 0; k < TAG; ++k) s += expf(stv[k] - m);
      float ls = logf(s);
      int am = 0;
      float bv = stv[0];
#pragma unroll
      for (int k = 1; k < TAG; ++k) {
        if (stv[k] > bv) { bv = stv[k]; am = k; }
      }
      pred = am;
      if (b == 0) {
        if (tid < TAG) {
          float lp = stv[tid] - m - ls;
          out[OUT_LOGP + t * TAG + tid] = lp;
          out[OUT_PROB + t * TAG + tid] = expf(lp);
        } else if (tid == TAG) {
          out[OUT_PRED + t] = (float)am;
        }
      }
      __syncthreads();
    }
  }
}

extern "C" void kernel_launch(void* const* d_in, const int* in_sizes, int n_in,
                              void* d_out, int out_size, void* d_ws, size_t ws_size,
                              hipStream_t stream) {
  const float* seq = (const float*)d_in[0];
  const float* W_embed = (const float*)d_in[1];
  const float* b_embed = (const float*)d_in[2];
  const float* W_ih = (const float*)d_in[3];
  const float* W_hh = (const float*)d_in[4];
  const float* b_ih = (const float*)d_in[5];
  const float* b_hh = (const float*)d_in[6];
  const float* W_interm = (const float*)d_in[7];
  const float* b_interm = (const float*)d_in[8];
  const float* W_tag = (const float*)d_in[9];
  const float* b_tag = (const float*)d_in[10];
  (void)in_sizes; (void)n_in; (void)out_size; (void)ws_size;

  char* ws = (char*)d_ws;
  unsigned* arr = (unsigned*)(ws + WS_ARR);
  float* hbuf = (float*)(ws + WS_HBUF);
  float* tpg = (float*)(ws + WS_TP);
  float* VT = (float*)(ws + WS_VT);
  float* U = (float*)(ws + WS_U);
  float* out = (float*)d_out;

  // reset arrival flags, h buffers, tag partials every call (ws is poisoned)
  hipMemsetAsync(ws, 0, WS_ZERO, stream);

  hipLaunchKernelGGL(rnnss_vt_kernel, dim3((TAG * EMB) / 256), dim3(256), 0, stream,
                     W_embed, VT);
  hipLaunchKernelGGL(rnnss_uprep, dim3(T_STEPS / 64, EMB / 64), dim3(256), 0, stream,
                     seq, W_embed, b_embed, U);

  void* args[] = {
      (void*)&W_ih,    (void*)&W_hh,  (void*)&b_ih,  (void*)&b_hh,
      (void*)&W_interm,(void*)&b_interm, (void*)&W_tag, (void*)&b_tag,
      (void*)&U,       (void*)&VT,    (void*)&hbuf,  (void*)&tpg,
      (void*)&arr,     (void*)&out};
  hipLaunchCooperativeKernel((const void*)rnnss_persist, dim3(NBLK), dim3(NTHR),
                             args, 0, stream);
}